// Round 1
// baseline (240.721 us; speedup 1.0000x reference)
//
#include <hip/hip_runtime.h>
#include <hip/hip_fp16.h>

// Problem constants: B=16, S=1024, DIN=64, D=64
// out = [ z: 16*1024*64 fp32 | attn: 16*1024*1024 fp32 ]

typedef unsigned short u16;
typedef __attribute__((ext_vector_type(8))) short bhalf8;   // 8 bf16 (4 VGPRs) - MFMA A/B frag
typedef __attribute__((ext_vector_type(4))) float fx4;      // MFMA C/D frag

__device__ __forceinline__ u16 f2bf(float f) {
  union { float f; unsigned u; } v; v.f = f;
  unsigned r = v.u + 0x7FFFu + ((v.u >> 16) & 1u);  // RNE
  return (u16)(r >> 16);
}

__device__ __forceinline__ bhalf8 pack8(float4 a, float4 b) {
  bhalf8 r;
  r[0] = (short)f2bf(a.x); r[1] = (short)f2bf(a.y); r[2] = (short)f2bf(a.z); r[3] = (short)f2bf(a.w);
  r[4] = (short)f2bf(b.x); r[5] = (short)f2bf(b.y); r[6] = (short)f2bf(b.z); r[7] = (short)f2bf(b.w);
  return r;
}

// ---------------------------------------------------------------------------
// P1: q,k,v projections. grid 256, block 256. 64 rows/block, 4 threads/row.
// q,k -> bf16 (MFMA operands later), v -> fp32.
__global__ __launch_bounds__(256) void k_proj(
    const float* __restrict__ x, const float* __restrict__ Wq,
    const float* __restrict__ Wk, const float* __restrict__ Wv,
    u16* __restrict__ qbf, u16* __restrict__ kbf, float* __restrict__ vf)
{
  __shared__ float wl[3 * 4096];
  const int t = threadIdx.x;
  for (int c = t; c < 4096; c += 256) {
    wl[c] = Wq[c]; wl[4096 + c] = Wk[c]; wl[8192 + c] = Wv[c];
  }
  __syncthreads();
  const int row = blockIdx.x * 64 + (t >> 2);
  const int dbase = (t & 3) * 16;
  float xr[64];
  const float4* xp = (const float4*)(x + (size_t)row * 64);
#pragma unroll
  for (int c = 0; c < 16; ++c) {
    float4 v = xp[c];
    xr[4*c] = v.x; xr[4*c+1] = v.y; xr[4*c+2] = v.z; xr[4*c+3] = v.w;
  }
  float aq[16], ak[16], av[16];
#pragma unroll
  for (int m = 0; m < 16; ++m) { aq[m] = 0.f; ak[m] = 0.f; av[m] = 0.f; }
#pragma unroll  // full unroll: keeps xr[] in registers (no scratch)
  for (int f = 0; f < 64; ++f) {
    const float xv = xr[f];
    const float* wq = wl + f * 64 + dbase;
#pragma unroll
    for (int m = 0; m < 16; ++m) {
      aq[m] = fmaf(xv, wq[m], aq[m]);
      ak[m] = fmaf(xv, wq[4096 + m], ak[m]);
      av[m] = fmaf(xv, wq[8192 + m], av[m]);
    }
  }
  union { u16 u[16]; uint4 q[2]; } pq, pk;
#pragma unroll
  for (int m = 0; m < 16; ++m) { pq.u[m] = f2bf(aq[m]); pk.u[m] = f2bf(ak[m]); }
  const size_t o = (size_t)row * 64 + dbase;
  *(uint4*)(qbf + o) = pq.q[0]; *(uint4*)(qbf + o + 8) = pq.q[1];
  *(uint4*)(kbf + o) = pk.q[0]; *(uint4*)(kbf + o + 8) = pk.q[1];
  float4* vo = (float4*)(vf + o);
  vo[0] = make_float4(av[0], av[1], av[2], av[3]);
  vo[1] = make_float4(av[4], av[5], av[6], av[7]);
  vo[2] = make_float4(av[8], av[9], av[10], av[11]);
  vo[3] = make_float4(av[12], av[13], av[14], av[15]);
}

// ---------------------------------------------------------------------------
// P2: QK[b,i,j] = q[b,i].k[b,j] (unscaled), stored fp16 layout [i][b][j].
// grid 256 (b x i-tile64), block 256 (4 waves, wave = one 16-row m-tile).
__global__ __launch_bounds__(256) void k_qk(
    const u16* __restrict__ qbf, const u16* __restrict__ kbf, __half* __restrict__ qkw)
{
  const int t = threadIdx.x, l = t & 63, w = t >> 6;
  const int b = blockIdx.x & 15, it = blockIdx.x >> 4;
  const int lr = l & 15, lg = l >> 4;
  const int i0 = it * 64 + w * 16;
  const u16* qp = qbf + (size_t)(b * 1024 + i0 + lr) * 64 + lg * 8;
  bhalf8 a0 = *(const bhalf8*)(qp);
  bhalf8 a1 = *(const bhalf8*)(qp + 32);
  for (int jt = 0; jt < 64; ++jt) {
    const int j0 = jt * 16;
    const u16* kp = kbf + (size_t)(b * 1024 + j0 + lr) * 64 + lg * 8;
    bhalf8 b0 = *(const bhalf8*)(kp);
    bhalf8 b1 = *(const bhalf8*)(kp + 32);
    fx4 acc = {0.f, 0.f, 0.f, 0.f};
    acc = __builtin_amdgcn_mfma_f32_16x16x32_bf16(a0, b0, acc, 0, 0, 0);
    acc = __builtin_amdgcn_mfma_f32_16x16x32_bf16(a1, b1, acc, 0, 0, 0);
#pragma unroll
    for (int r = 0; r < 4; ++r) {
      const int i = i0 + lg * 4 + r;
      qkw[((size_t)i * 16 + b) * 1024 + j0 + lr] = __float2half(acc[r]);
    }
  }
}

// ---------------------------------------------------------------------------
// P3: per-i core. grid 1024 (i), block 256 (4 waves).
//  scores[b,j] = (QK_staged + Q_i @ aK_i^T) * 0.125 ; softmax over j ;
//  attn -> d_out ; z_a[b,d] = (1/l) * sum_j e[b,j]*aV[i,j,d] -> ws.
#define SLD 1028  // fp32 row stride: 16B-aligned rows, only 2-way bank aliasing
__global__ __launch_bounds__(256) void k_core(
    const float* __restrict__ aK, const float* __restrict__ aV,
    const u16* __restrict__ qbf, const __half* __restrict__ qkw,
    float* __restrict__ attn_out, float* __restrict__ za)
{
  __shared__ float sl[16 * SLD];
  __shared__ float sinv[16];
  const int i = blockIdx.x;
  const int t = threadIdx.x, l = t & 63, w = t >> 6;
  const int lr = l & 15, lg = l >> 4;

  // phase 0: stage QK_i [16][1024] fp16 -> LDS fp32 (coalesced)
  const __half* qk = qkw + (size_t)i * 16384;
  for (int c = t; c < 16384; c += 256)
    sl[(c >> 10) * SLD + (c & 1023)] = __half2float(qk[c]);

  // A-frags: Q_i rows b (A[m=b][k=d])
  const u16* qp = qbf + (size_t)(lr * 1024 + i) * 64 + lg * 8;
  bhalf8 a0 = *(const bhalf8*)(qp);
  bhalf8 a1 = *(const bhalf8*)(qp + 32);
  __syncthreads();

  // phase 1: += Q_i @ aK_i^T via MFMA; B-frags straight from global fp32->bf16.
  // Wave reads 16 full contiguous 256B aK rows per n-tile: each byte read once.
  for (int jt = w; jt < 64; jt += 4) {
    const int j0 = jt * 16;
    const float* ap = aK + ((size_t)i * 1024 + j0 + lr) * 64 + lg * 8;
    float4 c0 = *(const float4*)(ap);
    float4 c1 = *(const float4*)(ap + 4);
    float4 c2 = *(const float4*)(ap + 32);
    float4 c3 = *(const float4*)(ap + 36);
    bhalf8 b0 = pack8(c0, c1);
    bhalf8 b1 = pack8(c2, c3);
    fx4 acc = {0.f, 0.f, 0.f, 0.f};
    acc = __builtin_amdgcn_mfma_f32_16x16x32_bf16(a0, b0, acc, 0, 0, 0);
    acc = __builtin_amdgcn_mfma_f32_16x16x32_bf16(a1, b1, acc, 0, 0, 0);
#pragma unroll
    for (int r = 0; r < 4; ++r) {      // C: col=lane&15 (j), row=(lane>>4)*4+r (b)
      const int bb = lg * 4 + r;
      const int j = j0 + lr;
      sl[bb * SLD + j] = (sl[bb * SLD + j] + acc[r]) * 0.125f;
    }
  }
  __syncthreads();

  // phase 2: softmax per row; wave w owns rows w*4..w*4+3.
#pragma unroll
  for (int rr = 0; rr < 4; ++rr) {
    const int bb = w * 4 + rr;
    float e[16];
    float m = -3.0e30f;
#pragma unroll
    for (int c = 0; c < 16; ++c) { e[c] = sl[bb * SLD + c * 64 + l]; m = fmaxf(m, e[c]); }
#pragma unroll
    for (int off = 32; off; off >>= 1) m = fmaxf(m, __shfl_xor(m, off));
    float s = 0.f;
#pragma unroll
    for (int c = 0; c < 16; ++c) { e[c] = __expf(e[c] - m); s += e[c]; sl[bb * SLD + c * 64 + l] = e[c]; }
#pragma unroll
    for (int off = 32; off; off >>= 1) s += __shfl_xor(s, off);
    const float inv = 1.0f / s;
    if (l == 0) sinv[bb] = inv;
    float* ao = attn_out + ((size_t)bb * 1024 + i) * 1024;
#pragma unroll
    for (int c = 0; c < 16; ++c) ao[c * 64 + l] = e[c] * inv;
  }
  __syncthreads();

  // phase 3: z_a[b,d] = inv_l * sum_j e[b,j] * aV[i,j,d].  lane=d, wave owns
  // b in {w, w+4, w+8, w+12}. aV rows read coalesced 256B; e via LDS b128.
  const int d = l;
  const float* avp = aV + (size_t)i * 65536 + d;
  const float* r0 = sl + (size_t)(w + 0) * SLD;
  const float* r1 = sl + (size_t)(w + 4) * SLD;
  const float* r2 = sl + (size_t)(w + 8) * SLD;
  const float* r3 = sl + (size_t)(w + 12) * SLD;
  float z0 = 0.f, z1 = 0.f, z2 = 0.f, z3 = 0.f;
  for (int j = 0; j < 1024; j += 4) {
    float4 e0 = *(const float4*)(r0 + j);
    float4 e1 = *(const float4*)(r1 + j);
    float4 e2 = *(const float4*)(r2 + j);
    float4 e3 = *(const float4*)(r3 + j);
    float av0 = avp[(size_t)(j + 0) * 64];
    float av1 = avp[(size_t)(j + 1) * 64];
    float av2 = avp[(size_t)(j + 2) * 64];
    float av3 = avp[(size_t)(j + 3) * 64];
    z0 = fmaf(e0.x, av0, z0); z0 = fmaf(e0.y, av1, z0); z0 = fmaf(e0.z, av2, z0); z0 = fmaf(e0.w, av3, z0);
    z1 = fmaf(e1.x, av0, z1); z1 = fmaf(e1.y, av1, z1); z1 = fmaf(e1.z, av2, z1); z1 = fmaf(e1.w, av3, z1);
    z2 = fmaf(e2.x, av0, z2); z2 = fmaf(e2.y, av1, z2); z2 = fmaf(e2.z, av2, z2); z2 = fmaf(e2.w, av3, z2);
    z3 = fmaf(e3.x, av0, z3); z3 = fmaf(e3.y, av1, z3); z3 = fmaf(e3.z, av2, z3); z3 = fmaf(e3.w, av3, z3);
  }
  za[((size_t)i * 16 + w + 0) * 64 + d] = z0 * sinv[w + 0];
  za[((size_t)i * 16 + w + 4) * 64 + d] = z1 * sinv[w + 4];
  za[((size_t)i * 16 + w + 8) * 64 + d] = z2 * sinv[w + 8];
  za[((size_t)i * 16 + w + 12) * 64 + d] = z3 * sinv[w + 12];
}

// ---------------------------------------------------------------------------
// P4: z[b,i,d] = attn[b,i,:] @ v[b,:,d] + z_a[i,b,d].
// grid 256 (b x i-tile64), block 256. v transposed through LDS (stride 40:
// 2-way bank aliasing only). attn read fp32->bf16 as A-frags (128B/row segs).
__global__ __launch_bounds__(256) void k_zv(
    const float* __restrict__ attn, const float* __restrict__ vf,
    const float* __restrict__ za, float* __restrict__ zout)
{
  __shared__ __align__(16) u16 vt[64 * 40];
  const int t = threadIdx.x, l = t & 63, w = t >> 6;
  const int b = blockIdx.x & 15, it = blockIdx.x >> 4;
  const int lr = l & 15, lg = l >> 4;
  const int iw = it * 64 + w * 16;
  fx4 acc[4];
#pragma unroll
  for (int n = 0; n < 4; ++n) acc[n] = (fx4){0.f, 0.f, 0.f, 0.f};
  const int jl = t >> 3;
  const int c0 = (t & 7) * 8;
  for (int ks = 0; ks < 32; ++ks) {
    const int j0 = ks * 32;
    const float* vp = vf + (size_t)(b * 1024 + j0 + jl) * 64 + c0;
    float4 v0 = *(const float4*)(vp);
    float4 v1 = *(const float4*)(vp + 4);
    __syncthreads();   // previous iteration's B-frag reads complete
    vt[(c0 + 0) * 40 + jl] = f2bf(v0.x);
    vt[(c0 + 1) * 40 + jl] = f2bf(v0.y);
    vt[(c0 + 2) * 40 + jl] = f2bf(v0.z);
    vt[(c0 + 3) * 40 + jl] = f2bf(v0.w);
    vt[(c0 + 4) * 40 + jl] = f2bf(v1.x);
    vt[(c0 + 5) * 40 + jl] = f2bf(v1.y);
    vt[(c0 + 6) * 40 + jl] = f2bf(v1.z);
    vt[(c0 + 7) * 40 + jl] = f2bf(v1.w);
    __syncthreads();
    const float* apr = attn + (size_t)(b * 1024 + iw + lr) * 1024 + j0 + lg * 8;
    float4 t0 = *(const float4*)(apr);
    float4 t1 = *(const float4*)(apr + 4);
    bhalf8 af = pack8(t0, t1);
#pragma unroll
    for (int n = 0; n < 4; ++n) {
      bhalf8 bf = *(const bhalf8*)(vt + (n * 16 + lr) * 40 + lg * 8);
      acc[n] = __builtin_amdgcn_mfma_f32_16x16x32_bf16(af, bf, acc[n], 0, 0, 0);
    }
  }
#pragma unroll
  for (int n = 0; n < 4; ++n) {
#pragma unroll
    for (int r = 0; r < 4; ++r) {
      const int i = iw + lg * 4 + r;
      const int dd = n * 16 + lr;
      zout[((size_t)b * 1024 + i) * 64 + dd] = acc[n][r] + za[((size_t)i * 16 + b) * 64 + dd];
    }
  }
}

// ---------------------------------------------------------------------------
extern "C" void kernel_launch(void* const* d_in, const int* in_sizes, int n_in,
                              void* d_out, int out_size, void* d_ws, size_t ws_size,
                              hipStream_t stream)
{
  const float* x  = (const float*)d_in[0];
  const float* Wq = (const float*)d_in[1];
  const float* Wk = (const float*)d_in[2];
  const float* Wv = (const float*)d_in[3];
  const float* aK = (const float*)d_in[4];
  const float* aV = (const float*)d_in[5];
  float* zout = (float*)d_out;
  float* attn_out = zout + (size_t)16 * 1024 * 64;   // attn after z

  char* ws = (char*)d_ws;                 // layout (44 MB total):
  u16*    qbf = (u16*)(ws);                               //  0.. 2 MB q bf16
  u16*    kbf = (u16*)(ws + (size_t)2  * 1024 * 1024);    //  2.. 4 MB k bf16
  float*  vf  = (float*)(ws + (size_t)4  * 1024 * 1024);  //  4.. 8 MB v fp32
  float*  za  = (float*)(ws + (size_t)8  * 1024 * 1024);  //  8..12 MB z_a [i][b][d]
  __half* qkw = (__half*)(ws + (size_t)12 * 1024 * 1024); // 12..44 MB QK fp16 [i][b][j]

  hipLaunchKernelGGL(k_proj, dim3(256),  dim3(256), 0, stream, x, Wq, Wk, Wv, qbf, kbf, vf);
  hipLaunchKernelGGL(k_qk,   dim3(256),  dim3(256), 0, stream, qbf, kbf, qkw);
  hipLaunchKernelGGL(k_core, dim3(1024), dim3(256), 0, stream, aK, aV, qbf, qkw, attn_out, za);
  hipLaunchKernelGGL(k_zv,   dim3(256),  dim3(256), 0, stream, attn_out, vf, za, zout);
}

// Round 2
// 229.957 us; speedup vs baseline: 1.0468x; 1.0468x over previous
//
#include <hip/hip_runtime.h>
#include <hip/hip_fp16.h>
#include <hip/hip_bf16.h>

// Problem constants: B=16, S=1024, DIN=64, D=64
// out = [ z: 16*1024*64 fp32 | attn: 16*1024*1024 fp32 ]

typedef unsigned short u16;
typedef __attribute__((ext_vector_type(8))) short bhalf8;   // 8 bf16 (4 VGPRs) - MFMA A/B frag
typedef __attribute__((ext_vector_type(4))) float fx4;      // MFMA C/D frag

__device__ __forceinline__ short b16(float f) {             // RNE; compiler can fuse pairs
  __hip_bfloat16 h = __float2bfloat16(f);                   // into v_cvt_pk_bf16_f32
  return *reinterpret_cast<short*>(&h);
}

__device__ __forceinline__ bhalf8 pack8(float4 a, float4 b) {
  bhalf8 r;
  r[0] = b16(a.x); r[1] = b16(a.y); r[2] = b16(a.z); r[3] = b16(a.w);
  r[4] = b16(b.x); r[5] = b16(b.y); r[6] = b16(b.z); r[7] = b16(b.w);
  return r;
}

// ---------------------------------------------------------------------------
// P1: q,k,v projections. grid 256, block 256. 64 rows/block, 4 threads/row.
__global__ __launch_bounds__(256) void k_proj(
    const float* __restrict__ x, const float* __restrict__ Wq,
    const float* __restrict__ Wk, const float* __restrict__ Wv,
    u16* __restrict__ qbf, u16* __restrict__ kbf, float* __restrict__ vf)
{
  __shared__ float wl[3 * 4096];
  const int t = threadIdx.x;
  for (int c = t; c < 4096; c += 256) {
    wl[c] = Wq[c]; wl[4096 + c] = Wk[c]; wl[8192 + c] = Wv[c];
  }
  __syncthreads();
  const int row = blockIdx.x * 64 + (t >> 2);
  const int dbase = (t & 3) * 16;
  float xr[64];
  const float4* xp = (const float4*)(x + (size_t)row * 64);
#pragma unroll
  for (int c = 0; c < 16; ++c) {
    float4 v = xp[c];
    xr[4*c] = v.x; xr[4*c+1] = v.y; xr[4*c+2] = v.z; xr[4*c+3] = v.w;
  }
  float aq[16], ak[16], av[16];
#pragma unroll
  for (int m = 0; m < 16; ++m) { aq[m] = 0.f; ak[m] = 0.f; av[m] = 0.f; }
#pragma unroll
  for (int f = 0; f < 64; ++f) {
    const float xv = xr[f];
    const float* wq = wl + f * 64 + dbase;
#pragma unroll
    for (int m = 0; m < 16; ++m) {
      aq[m] = fmaf(xv, wq[m], aq[m]);
      ak[m] = fmaf(xv, wq[4096 + m], ak[m]);
      av[m] = fmaf(xv, wq[8192 + m], av[m]);
    }
  }
  union { u16 u[16]; uint4 q[2]; } pq, pk;
#pragma unroll
  for (int m = 0; m < 16; ++m) { pq.u[m] = (u16)b16(aq[m]); pk.u[m] = (u16)b16(ak[m]); }
  const size_t o = (size_t)row * 64 + dbase;
  *(uint4*)(qbf + o) = pq.q[0]; *(uint4*)(qbf + o + 8) = pq.q[1];
  *(uint4*)(kbf + o) = pk.q[0]; *(uint4*)(kbf + o + 8) = pk.q[1];
  float4* vo = (float4*)(vf + o);
  vo[0] = make_float4(av[0], av[1], av[2], av[3]);
  vo[1] = make_float4(av[4], av[5], av[6], av[7]);
  vo[2] = make_float4(av[8], av[9], av[10], av[11]);
  vo[3] = make_float4(av[12], av[13], av[14], av[15]);
}

// ---------------------------------------------------------------------------
// P2: QK[b,i,j] = q[b,i].k[b,j] (unscaled), stored fp16 layout [i][b][j].
__global__ __launch_bounds__(256) void k_qk(
    const u16* __restrict__ qbf, const u16* __restrict__ kbf, __half* __restrict__ qkw)
{
  const int t = threadIdx.x, l = t & 63, w = t >> 6;
  const int b = blockIdx.x & 15, it = blockIdx.x >> 4;
  const int lr = l & 15, lg = l >> 4;
  const int i0 = it * 64 + w * 16;
  const u16* qp = qbf + (size_t)(b * 1024 + i0 + lr) * 64 + lg * 8;
  bhalf8 a0 = *(const bhalf8*)(qp);
  bhalf8 a1 = *(const bhalf8*)(qp + 32);
  for (int jt = 0; jt < 64; ++jt) {
    const int j0 = jt * 16;
    const u16* kp = kbf + (size_t)(b * 1024 + j0 + lr) * 64 + lg * 8;
    bhalf8 b0 = *(const bhalf8*)(kp);
    bhalf8 b1 = *(const bhalf8*)(kp + 32);
    fx4 acc = {0.f, 0.f, 0.f, 0.f};
    acc = __builtin_amdgcn_mfma_f32_16x16x32_bf16(a0, b0, acc, 0, 0, 0);
    acc = __builtin_amdgcn_mfma_f32_16x16x32_bf16(a1, b1, acc, 0, 0, 0);
#pragma unroll
    for (int r = 0; r < 4; ++r) {
      const int i = i0 + lg * 4 + r;
      qkw[((size_t)i * 16 + b) * 1024 + j0 + lr] = __float2half(acc[r]);
    }
  }
}

// ---------------------------------------------------------------------------
// P3: per-i core, j processed in two halves of 512 with online softmax merge.
// LDS = 16x516 f32 (33 KB) -> 4 blocks/CU (grid 1024 fully resident).
//  per half: stage qk -> LDS, MFMA += Q_i @ aK^T, stats (+e in place),
//  aV contraction with j split across the 4 waves (no redundant reads).
//  attn half-0 written raw (e1), fixed up at the end by the writing thread.
#define SLD2 516  // f32 row stride: 16B-aligned rows, 2-way bank aliasing only
__global__ __launch_bounds__(256, 4) void k_core(
    const float* __restrict__ aK, const float* __restrict__ aV,
    const u16* __restrict__ qbf, const __half* __restrict__ qkw,
    float* __restrict__ attn_out, float* __restrict__ za)
{
  __shared__ float sl[16 * SLD2];   // 33,024 B
  __shared__ float stats[64];       // [0:16) m1, [16:32) s1, [32:48) corr, [48:64) inv
  const int i = blockIdx.x;
  const int t = threadIdx.x, l = t & 63, w = t >> 6;
  const int lr = l & 15, lg = l >> 4;

  // A-frags: Q rows b=lr at position i  (A[m=b][k=d])
  const u16* qp = qbf + (size_t)(lr * 1024 + i) * 64 + lg * 8;
  bhalf8 a0 = *(const bhalf8*)(qp);
  bhalf8 a1 = *(const bhalf8*)(qp + 32);

  float zc[16];
#pragma unroll
  for (int b = 0; b < 16; ++b) zc[b] = 0.f;

  for (int h = 0; h < 2; ++h) {
    // ---- stage qk half: vectorized fp16 loads (16 B/lane), f32 into LDS
    const __half* qk = qkw + (size_t)i * 16384 + h * 512;
    for (int c = t; c < 1024; c += 256) {
      const int b = c >> 6;                 // 64 uint4-chunks per 512-row
      const int j8 = (c & 63) * 8;
      const __half2* hp = (const __half2*)(qk + (size_t)b * 1024 + j8);
      float2 f0 = __half22float2(hp[0]);
      float2 f1 = __half22float2(hp[1]);
      float2 f2 = __half22float2(hp[2]);
      float2 f3 = __half22float2(hp[3]);
      float* dst = sl + b * SLD2 + j8;
      *(float4*)(dst)     = make_float4(f0.x, f0.y, f1.x, f1.y);
      *(float4*)(dst + 4) = make_float4(f2.x, f2.y, f3.x, f3.y);
    }
    __syncthreads();

    // ---- MFMA: += Q_i @ aK_half^T ; wave w owns local tiles jt = w+4*tt
    for (int tt = 0; tt < 8; ++tt) {
      const int j0 = (w + tt * 4) * 16;   // local col base within half
      const float* ap = aK + ((size_t)i * 1024 + h * 512 + j0 + lr) * 64 + lg * 8;
      float4 c0 = *(const float4*)(ap);
      float4 c1 = *(const float4*)(ap + 4);
      float4 c2 = *(const float4*)(ap + 32);
      float4 c3 = *(const float4*)(ap + 36);
      fx4 acc = {0.f, 0.f, 0.f, 0.f};
      acc = __builtin_amdgcn_mfma_f32_16x16x32_bf16(a0, pack8(c0, c1), acc, 0, 0, 0);
      acc = __builtin_amdgcn_mfma_f32_16x16x32_bf16(a1, pack8(c2, c3), acc, 0, 0, 0);
#pragma unroll
      for (int r = 0; r < 4; ++r)          // C: col=lane&15 (j), row=(lane>>4)*4+r (b)
        sl[(lg * 4 + r) * SLD2 + j0 + lr] += acc[r];
    }
    __syncthreads();

    // ---- stats: wave w owns rows w*4..w*4+3 (raw scores; scale by 0.125 in exp)
    if (h == 0) {
#pragma unroll
      for (int rr = 0; rr < 4; ++rr) {
        const int row = w * 4 + rr;
        float* rp = sl + row * SLD2;
        float v8[8]; float mx = -3.0e30f;
#pragma unroll
        for (int c = 0; c < 8; ++c) { v8[c] = rp[c * 64 + l]; mx = fmaxf(mx, v8[c]); }
#pragma unroll
        for (int off = 32; off; off >>= 1) mx = fmaxf(mx, __shfl_xor(mx, off));
        float sum = 0.f;
        float* ao = attn_out + ((size_t)row * 1024 + i) * 1024;
#pragma unroll
        for (int c = 0; c < 8; ++c) {
          float e = __expf((v8[c] - mx) * 0.125f);
          sum += e; rp[c * 64 + l] = e;
          ao[c * 64 + l] = e;               // raw e1; fixed up at end by THIS thread
        }
#pragma unroll
        for (int off = 32; off; off >>= 1) sum += __shfl_xor(sum, off);
        if (l == 0) { stats[row] = mx; stats[16 + row] = sum; }
      }
    } else {
#pragma unroll
      for (int rr = 0; rr < 4; ++rr) {
        const int row = w * 4 + rr;
        float* rp = sl + row * SLD2;
        float v8[8]; float mx = -3.0e30f;
#pragma unroll
        for (int c = 0; c < 8; ++c) { v8[c] = rp[c * 64 + l]; mx = fmaxf(mx, v8[c]); }
#pragma unroll
        for (int off = 32; off; off >>= 1) mx = fmaxf(mx, __shfl_xor(mx, off));
        const float m1 = stats[row];
        const float m  = fmaxf(m1, mx);
        const float corr = __expf((m1 - m) * 0.125f);
        float e8[8]; float sum = 0.f;
#pragma unroll
        for (int c = 0; c < 8; ++c) {
          e8[c] = __expf((v8[c] - m) * 0.125f);
          sum += e8[c]; rp[c * 64 + l] = e8[c];
        }
#pragma unroll
        for (int off = 32; off; off >>= 1) sum += __shfl_xor(sum, off);
        const float inv = 1.0f / (stats[16 + row] * corr + sum);
        float* ao = attn_out + ((size_t)row * 1024 + i) * 1024 + 512;
#pragma unroll
        for (int c = 0; c < 8; ++c) ao[c * 64 + l] = e8[c] * inv;   // final half-1
        if (l == 0) { stats[32 + row] = corr; stats[48 + row] = inv; }
      }
    }
    __syncthreads();

    // ---- aV contraction over this half's e (LDS broadcast reads), wave j-split
    if (h == 1) {
#pragma unroll
      for (int b = 0; b < 16; ++b) zc[b] *= stats[32 + b];   // rescale z1 by corr
    }
    const float* avp = aV + ((size_t)i * 1024 + h * 512 + w * 128) * 64 + l;  // lane=d
    for (int jg = 0; jg < 32; ++jg) {
      const int jl = w * 128 + jg * 4;
      float a0v = avp[(size_t)(jg * 4 + 0) * 64];
      float a1v = avp[(size_t)(jg * 4 + 1) * 64];
      float a2v = avp[(size_t)(jg * 4 + 2) * 64];
      float a3v = avp[(size_t)(jg * 4 + 3) * 64];
#pragma unroll
      for (int b = 0; b < 16; ++b) {
        float4 e4 = *(const float4*)(sl + b * SLD2 + jl);   // wave-uniform: broadcast
        zc[b] = fmaf(e4.x, a0v, zc[b]);
        zc[b] = fmaf(e4.y, a1v, zc[b]);
        zc[b] = fmaf(e4.z, a2v, zc[b]);
        zc[b] = fmaf(e4.w, a3v, zc[b]);
      }
    }
    __syncthreads();   // before next half (or reduce) reuses sl
  }

  // ---- cross-wave z reduction (reuse sl) + za write
#pragma unroll
  for (int b = 0; b < 16; ++b) sl[(w * 16 + b) * 64 + l] = zc[b];
  __syncthreads();
  for (int o = t; o < 1024; o += 256) {
    const int b = o >> 6, d = o & 63;
    float s = sl[b * 64 + d] + sl[(16 + b) * 64 + d]
            + sl[(32 + b) * 64 + d] + sl[(48 + b) * 64 + d];
    za[((size_t)i * 16 + b) * 64 + d] = s * stats[48 + b];
  }

  // ---- fixup attn half-0: same thread re-reads its own raw e1 writes (L2 RAW)
#pragma unroll
  for (int rr = 0; rr < 4; ++rr) {
    const int row = w * 4 + rr;
    const float f = stats[32 + row] * stats[48 + row];   // corr * inv
    float* ao = attn_out + ((size_t)row * 1024 + i) * 1024;
#pragma unroll
    for (int c = 0; c < 8; ++c) ao[c * 64 + l] *= f;
  }
}

// ---------------------------------------------------------------------------
// P4: z[b,i,d] = attn[b,i,:] @ v[b,:,d] + z_a[i,b,d].
__global__ __launch_bounds__(256) void k_zv(
    const float* __restrict__ attn, const float* __restrict__ vf,
    const float* __restrict__ za, float* __restrict__ zout)
{
  __shared__ __align__(16) u16 vt[64 * 40];
  const int t = threadIdx.x, l = t & 63, w = t >> 6;
  const int b = blockIdx.x & 15, it = blockIdx.x >> 4;
  const int lr = l & 15, lg = l >> 4;
  const int iw = it * 64 + w * 16;
  fx4 acc[4];
#pragma unroll
  for (int n = 0; n < 4; ++n) acc[n] = (fx4){0.f, 0.f, 0.f, 0.f};
  const int jl = t >> 3;
  const int c0 = (t & 7) * 8;
  for (int ks = 0; ks < 32; ++ks) {
    const int j0 = ks * 32;
    const float* vp = vf + (size_t)(b * 1024 + j0 + jl) * 64 + c0;
    float4 v0 = *(const float4*)(vp);
    float4 v1 = *(const float4*)(vp + 4);
    __syncthreads();
    vt[(c0 + 0) * 40 + jl] = (u16)b16(v0.x);
    vt[(c0 + 1) * 40 + jl] = (u16)b16(v0.y);
    vt[(c0 + 2) * 40 + jl] = (u16)b16(v0.z);
    vt[(c0 + 3) * 40 + jl] = (u16)b16(v0.w);
    vt[(c0 + 4) * 40 + jl] = (u16)b16(v1.x);
    vt[(c0 + 5) * 40 + jl] = (u16)b16(v1.y);
    vt[(c0 + 6) * 40 + jl] = (u16)b16(v1.z);
    vt[(c0 + 7) * 40 + jl] = (u16)b16(v1.w);
    __syncthreads();
    const float* apr = attn + (size_t)(b * 1024 + iw + lr) * 1024 + j0 + lg * 8;
    float4 t0 = *(const float4*)(apr);
    float4 t1 = *(const float4*)(apr + 4);
    bhalf8 af = pack8(t0, t1);
#pragma unroll
    for (int n = 0; n < 4; ++n) {
      bhalf8 bf = *(const bhalf8*)(vt + (n * 16 + lr) * 40 + lg * 8);
      acc[n] = __builtin_amdgcn_mfma_f32_16x16x32_bf16(af, bf, acc[n], 0, 0, 0);
    }
  }
#pragma unroll
  for (int n = 0; n < 4; ++n) {
#pragma unroll
    for (int r = 0; r < 4; ++r) {
      const int i = iw + lg * 4 + r;
      const int dd = n * 16 + lr;
      zout[((size_t)b * 1024 + i) * 64 + dd] = acc[n][r] + za[((size_t)i * 16 + b) * 64 + dd];
    }
  }
}

// ---------------------------------------------------------------------------
extern "C" void kernel_launch(void* const* d_in, const int* in_sizes, int n_in,
                              void* d_out, int out_size, void* d_ws, size_t ws_size,
                              hipStream_t stream)
{
  const float* x  = (const float*)d_in[0];
  const float* Wq = (const float*)d_in[1];
  const float* Wk = (const float*)d_in[2];
  const float* Wv = (const float*)d_in[3];
  const float* aK = (const float*)d_in[4];
  const float* aV = (const float*)d_in[5];
  float* zout = (float*)d_out;
  float* attn_out = zout + (size_t)16 * 1024 * 64;   // attn after z

  char* ws = (char*)d_ws;                 // layout (44 MB total):
  u16*    qbf = (u16*)(ws);                               //  0.. 2 MB q bf16
  u16*    kbf = (u16*)(ws + (size_t)2  * 1024 * 1024);    //  2.. 4 MB k bf16
  float*  vf  = (float*)(ws + (size_t)4  * 1024 * 1024);  //  4.. 8 MB v fp32
  float*  za  = (float*)(ws + (size_t)8  * 1024 * 1024);  //  8..12 MB z_a [i][b][d]
  __half* qkw = (__half*)(ws + (size_t)12 * 1024 * 1024); // 12..44 MB QK fp16 [i][b][j]

  hipLaunchKernelGGL(k_proj, dim3(256),  dim3(256), 0, stream, x, Wq, Wk, Wv, qbf, kbf, vf);
  hipLaunchKernelGGL(k_qk,   dim3(256),  dim3(256), 0, stream, qbf, kbf, qkw);
  hipLaunchKernelGGL(k_core, dim3(1024), dim3(256), 0, stream, aK, aV, qbf, qkw, attn_out, za);
  hipLaunchKernelGGL(k_zv,   dim3(256),  dim3(256), 0, stream, attn_out, vf, za, zout);
}

// Round 3
// 225.770 us; speedup vs baseline: 1.0662x; 1.0185x over previous
//
#include <hip/hip_runtime.h>
#include <hip/hip_fp16.h>
#include <hip/hip_bf16.h>

// Problem constants: B=16, S=1024, DIN=64, D=64
// out = [ z: 16*1024*64 fp32 | attn: 16*1024*1024 fp32 ]

typedef unsigned short u16;
typedef __attribute__((ext_vector_type(8))) short bhalf8;   // 8 bf16 (4 VGPRs) - MFMA A/B frag
typedef __attribute__((ext_vector_type(4))) float fx4;      // MFMA C/D frag

__device__ __forceinline__ short b16(float f) {             // RNE; pairs fuse to v_cvt_pk_bf16_f32
  __hip_bfloat16 h = __float2bfloat16(f);
  return *reinterpret_cast<short*>(&h);
}

__device__ __forceinline__ bhalf8 pack8(float4 a, float4 b) {
  bhalf8 r;
  r[0] = b16(a.x); r[1] = b16(a.y); r[2] = b16(a.z); r[3] = b16(a.w);
  r[4] = b16(b.x); r[5] = b16(b.y); r[6] = b16(b.z); r[7] = b16(b.w);
  return r;
}

// ---------------------------------------------------------------------------
// P1: q,k,v projections. grid 256, block 256. 64 rows/block, 4 threads/row.
__global__ __launch_bounds__(256) void k_proj(
    const float* __restrict__ x, const float* __restrict__ Wq,
    const float* __restrict__ Wk, const float* __restrict__ Wv,
    u16* __restrict__ qbf, u16* __restrict__ kbf, float* __restrict__ vf)
{
  __shared__ float wl[3 * 4096];
  const int t = threadIdx.x;
  for (int c = t; c < 4096; c += 256) {
    wl[c] = Wq[c]; wl[4096 + c] = Wk[c]; wl[8192 + c] = Wv[c];
  }
  __syncthreads();
  const int row = blockIdx.x * 64 + (t >> 2);
  const int dbase = (t & 3) * 16;
  float xr[64];
  const float4* xp = (const float4*)(x + (size_t)row * 64);
#pragma unroll
  for (int c = 0; c < 16; ++c) {
    float4 v = xp[c];
    xr[4*c] = v.x; xr[4*c+1] = v.y; xr[4*c+2] = v.z; xr[4*c+3] = v.w;
  }
  float aq[16], ak[16], av[16];
#pragma unroll
  for (int m = 0; m < 16; ++m) { aq[m] = 0.f; ak[m] = 0.f; av[m] = 0.f; }
#pragma unroll
  for (int f = 0; f < 64; ++f) {
    const float xv = xr[f];
    const float* wq = wl + f * 64 + dbase;
#pragma unroll
    for (int m = 0; m < 16; ++m) {
      aq[m] = fmaf(xv, wq[m], aq[m]);
      ak[m] = fmaf(xv, wq[4096 + m], ak[m]);
      av[m] = fmaf(xv, wq[8192 + m], av[m]);
    }
  }
  union { u16 u[16]; uint4 q[2]; } pq, pk;
#pragma unroll
  for (int m = 0; m < 16; ++m) { pq.u[m] = (u16)b16(aq[m]); pk.u[m] = (u16)b16(ak[m]); }
  const size_t o = (size_t)row * 64 + dbase;
  *(uint4*)(qbf + o) = pq.q[0]; *(uint4*)(qbf + o + 8) = pq.q[1];
  *(uint4*)(kbf + o) = pk.q[0]; *(uint4*)(kbf + o + 8) = pk.q[1];
  float4* vo = (float4*)(vf + o);
  vo[0] = make_float4(av[0], av[1], av[2], av[3]);
  vo[1] = make_float4(av[4], av[5], av[6], av[7]);
  vo[2] = make_float4(av[8], av[9], av[10], av[11]);
  vo[3] = make_float4(av[12], av[13], av[14], av[15]);
}

// ---------------------------------------------------------------------------
// P2: QK[b,i,j] = q[b,i].k[b,j] (unscaled), stored fp16 layout [i][b][j].
__global__ __launch_bounds__(256) void k_qk(
    const u16* __restrict__ qbf, const u16* __restrict__ kbf, __half* __restrict__ qkw)
{
  const int t = threadIdx.x, l = t & 63, w = t >> 6;
  const int b = blockIdx.x & 15, it = blockIdx.x >> 4;
  const int lr = l & 15, lg = l >> 4;
  const int i0 = it * 64 + w * 16;
  const u16* qp = qbf + (size_t)(b * 1024 + i0 + lr) * 64 + lg * 8;
  bhalf8 a0 = *(const bhalf8*)(qp);
  bhalf8 a1 = *(const bhalf8*)(qp + 32);
  for (int jt = 0; jt < 64; ++jt) {
    const int j0 = jt * 16;
    const u16* kp = kbf + (size_t)(b * 1024 + j0 + lr) * 64 + lg * 8;
    bhalf8 b0 = *(const bhalf8*)(kp);
    bhalf8 b1 = *(const bhalf8*)(kp + 32);
    fx4 acc = {0.f, 0.f, 0.f, 0.f};
    acc = __builtin_amdgcn_mfma_f32_16x16x32_bf16(a0, b0, acc, 0, 0, 0);
    acc = __builtin_amdgcn_mfma_f32_16x16x32_bf16(a1, b1, acc, 0, 0, 0);
#pragma unroll
    for (int r = 0; r < 4; ++r) {
      const int i = i0 + lg * 4 + r;
      qkw[((size_t)i * 16 + b) * 1024 + j0 + lr] = __float2half(acc[r]);
    }
  }
}

// ---------------------------------------------------------------------------
// P3: per-i core, j in two halves of 512, online softmax merge, PV via MFMA.
// LDS: sl 16x516 f32 (scores; row head doubles as e-bf16[512] for PV A-frags)
//      vt 64x40 u16  (aV^T 32j-tile, bf16, PADJ=40 -> 16B-aligned rows)
// Total 38.4 KB -> 4 blocks/CU. grid 1024 fully resident.
#define SLD2 516
#define PADJ 40
__global__ __launch_bounds__(256, 4) void k_core(
    const float* __restrict__ aK, const float* __restrict__ aV,
    const u16* __restrict__ qbf, const __half* __restrict__ qkw,
    float* __restrict__ attn_out, float* __restrict__ za)
{
  __shared__ __align__(16) float sl[16 * SLD2];   // 33,024 B
  __shared__ __align__(16) u16 vt[64 * PADJ];     //  5,120 B
  __shared__ float stats[64];  // [0:16) m1, [16:32) s1, [32:48) corr, [48:64) inv
  const int i = blockIdx.x;
  const int t = threadIdx.x, l = t & 63, w = t >> 6;
  const int lr = l & 15, lg = l >> 4;

  // A-frags: Q rows b=lr at position i  (A[m=b][k=d])
  const u16* qp = qbf + (size_t)(lr * 1024 + i) * 64 + lg * 8;
  bhalf8 a0 = *(const bhalf8*)(qp);
  bhalf8 a1 = *(const bhalf8*)(qp + 32);

  fx4 zacc = {0.f, 0.f, 0.f, 0.f};   // D[m=b][n=d] partial: b=lg*4+r, d=w*16+lr

  // PV staging mapping: thread t owns (jA = t>>4 in 0..15, dA = (t&15)*4)
  const int jA = t >> 4;
  const int dA = (t & 15) * 4;

  for (int h = 0; h < 2; ++h) {
    // ---- stage qk half -> sl f32 (16B uint4 loads)
    const __half* qk = qkw + (size_t)i * 16384 + h * 512;
    for (int c = t; c < 1024; c += 256) {
      const int b = c >> 6;
      const int j8 = (c & 63) * 8;
      uint4 u = *(const uint4*)(qk + (size_t)b * 1024 + j8);
      const __half2* hh = (const __half2*)&u;
      float2 f0 = __half22float2(hh[0]);
      float2 f1 = __half22float2(hh[1]);
      float2 f2 = __half22float2(hh[2]);
      float2 f3 = __half22float2(hh[3]);
      float* dst = sl + b * SLD2 + j8;
      *(float4*)(dst)     = make_float4(f0.x, f0.y, f1.x, f1.y);
      *(float4*)(dst + 4) = make_float4(f2.x, f2.y, f3.x, f3.y);
    }
    __syncthreads();

    // ---- MFMA: += Q_i @ aK_half^T ; wave w owns local tiles jt = w+4*tt
    for (int tt = 0; tt < 8; ++tt) {
      const int j0 = (w + tt * 4) * 16;
      const float* ap = aK + ((size_t)i * 1024 + h * 512 + j0 + lr) * 64 + lg * 8;
      float4 c0 = *(const float4*)(ap);
      float4 c1 = *(const float4*)(ap + 4);
      float4 c2 = *(const float4*)(ap + 32);
      float4 c3 = *(const float4*)(ap + 36);
      fx4 acc = {0.f, 0.f, 0.f, 0.f};
      acc = __builtin_amdgcn_mfma_f32_16x16x32_bf16(a0, pack8(c0, c1), acc, 0, 0, 0);
      acc = __builtin_amdgcn_mfma_f32_16x16x32_bf16(a1, pack8(c2, c3), acc, 0, 0, 0);
#pragma unroll
      for (int r = 0; r < 4; ++r)          // C: col=lane&15 (j), row=(lane>>4)*4+r (b)
        sl[(lg * 4 + r) * SLD2 + j0 + lr] += acc[r];
    }
    __syncthreads();

    // ---- softmax stats; wave w owns rows w*4..w*4+3; lane covers j = l*8..l*8+8.
    // Writes raw-e attn (h0) / final attn (h1), and raw-e bf16 into the row HEAD
    // (bytes [0,1024) of the row) for the PV A-frags. In-wave read-before-write.
    if (h == 0) {
#pragma unroll
      for (int rr = 0; rr < 4; ++rr) {
        const int row = w * 4 + rr;
        float* rp = sl + row * SLD2;
        float4 x0 = *(const float4*)(rp + l * 8);
        float4 x1 = *(const float4*)(rp + l * 8 + 4);
        float v8[8] = {x0.x, x0.y, x0.z, x0.w, x1.x, x1.y, x1.z, x1.w};
        float mx = -3.0e30f;
#pragma unroll
        for (int c = 0; c < 8; ++c) mx = fmaxf(mx, v8[c]);
#pragma unroll
        for (int off = 32; off; off >>= 1) mx = fmaxf(mx, __shfl_xor(mx, off));
        float e8[8]; float sum = 0.f;
#pragma unroll
        for (int c = 0; c < 8; ++c) { e8[c] = __expf((v8[c] - mx) * 0.125f); sum += e8[c]; }
        float* ao = attn_out + ((size_t)row * 1024 + i) * 1024;
        *(float4*)(ao + l * 8)     = make_float4(e8[0], e8[1], e8[2], e8[3]);  // raw e1
        *(float4*)(ao + l * 8 + 4) = make_float4(e8[4], e8[5], e8[6], e8[7]);
        bhalf8 eb;
#pragma unroll
        for (int c = 0; c < 8; ++c) eb[c] = b16(e8[c]);
        *(bhalf8*)((u16*)rp + l * 8) = eb;                  // e-bf16 row head
#pragma unroll
        for (int off = 32; off; off >>= 1) sum += __shfl_xor(sum, off);
        if (l == 0) { stats[row] = mx; stats[16 + row] = sum; }
      }
    } else {
#pragma unroll
      for (int rr = 0; rr < 4; ++rr) {
        const int row = w * 4 + rr;
        float* rp = sl + row * SLD2;
        float4 x0 = *(const float4*)(rp + l * 8);
        float4 x1 = *(const float4*)(rp + l * 8 + 4);
        float v8[8] = {x0.x, x0.y, x0.z, x0.w, x1.x, x1.y, x1.z, x1.w};
        float mx = -3.0e30f;
#pragma unroll
        for (int c = 0; c < 8; ++c) mx = fmaxf(mx, v8[c]);
#pragma unroll
        for (int off = 32; off; off >>= 1) mx = fmaxf(mx, __shfl_xor(mx, off));
        const float m1 = stats[row];
        const float m  = fmaxf(m1, mx);
        const float corr = __expf((m1 - m) * 0.125f);
        float e8[8]; float sum = 0.f;
#pragma unroll
        for (int c = 0; c < 8; ++c) { e8[c] = __expf((v8[c] - m) * 0.125f); sum += e8[c]; }
        bhalf8 eb;
#pragma unroll
        for (int c = 0; c < 8; ++c) eb[c] = b16(e8[c]);
        *(bhalf8*)((u16*)rp + l * 8) = eb;                  // raw e2 for PV
#pragma unroll
        for (int off = 32; off; off >>= 1) sum += __shfl_xor(sum, off);
        const float inv = 1.0f / (stats[16 + row] * corr + sum);
        float* ao = attn_out + ((size_t)row * 1024 + i) * 1024 + 512;
        *(float4*)(ao + l * 8)     = make_float4(e8[0]*inv, e8[1]*inv, e8[2]*inv, e8[3]*inv);
        *(float4*)(ao + l * 8 + 4) = make_float4(e8[4]*inv, e8[5]*inv, e8[6]*inv, e8[7]*inv);
        if (l == 0) { stats[32 + row] = corr; stats[48 + row] = inv; }
      }
    }
    __syncthreads();

    // ---- PV: zacc += e_bf16 @ aV_half ; 16 tiles of 32 j, aV^T staged in vt.
    // Wave w owns n-tile d = w*16..w*16+16 (no cross-wave reduce needed).
    if (h == 1) {
#pragma unroll
      for (int r = 0; r < 4; ++r) zacc[r] *= stats[32 + lg * 4 + r];   // corr
    }
    float4 pa, pb;
    {
      const float* ap = aV + ((size_t)i * 1024 + h * 512 + jA) * 64 + dA;
      pa = *(const float4*)(ap);
      pb = *(const float4*)(ap + 1024);   // +16 rows
    }
    for (int it = 0; it < 16; ++it) {
      __syncthreads();     // previous tile's B-frag reads complete
      vt[(dA + 0) * PADJ + jA] = (u16)b16(pa.x);
      vt[(dA + 1) * PADJ + jA] = (u16)b16(pa.y);
      vt[(dA + 2) * PADJ + jA] = (u16)b16(pa.z);
      vt[(dA + 3) * PADJ + jA] = (u16)b16(pa.w);
      vt[(dA + 0) * PADJ + jA + 16] = (u16)b16(pb.x);
      vt[(dA + 1) * PADJ + jA + 16] = (u16)b16(pb.y);
      vt[(dA + 2) * PADJ + jA + 16] = (u16)b16(pb.z);
      vt[(dA + 3) * PADJ + jA + 16] = (u16)b16(pb.w);
      if (it < 15) {
        const float* ap = aV + ((size_t)i * 1024 + h * 512 + (it + 1) * 32 + jA) * 64 + dA;
        pa = *(const float4*)(ap);
        pb = *(const float4*)(ap + 1024);
      }
      __syncthreads();     // vt ready
      bhalf8 ea = *(const bhalf8*)((const u16*)(sl + (size_t)lr * SLD2) + it * 32 + lg * 8);
      bhalf8 bv = *(const bhalf8*)(vt + (w * 16 + lr) * PADJ + lg * 8);
      zacc = __builtin_amdgcn_mfma_f32_16x16x32_bf16(ea, bv, zacc, 0, 0, 0);
    }
    __syncthreads();       // before next-half staging overwrites sl
  }

  // ---- za directly from accumulator: b = lg*4+r, d = w*16+lr
#pragma unroll
  for (int r = 0; r < 4; ++r) {
    const int b = lg * 4 + r;
    za[((size_t)i * 16 + b) * 64 + w * 16 + lr] = zacc[r] * stats[48 + b];
  }

  // ---- fixup attn half-0: same thread re-reads its own raw e1 writes (L2 RAW)
#pragma unroll
  for (int rr = 0; rr < 4; ++rr) {
    const int row = w * 4 + rr;
    const float f = stats[32 + row] * stats[48 + row];   // corr * inv
    float* ao = attn_out + ((size_t)row * 1024 + i) * 1024;
    float4 u0 = *(const float4*)(ao + l * 8);
    float4 u1 = *(const float4*)(ao + l * 8 + 4);
    *(float4*)(ao + l * 8)     = make_float4(u0.x*f, u0.y*f, u0.z*f, u0.w*f);
    *(float4*)(ao + l * 8 + 4) = make_float4(u1.x*f, u1.y*f, u1.z*f, u1.w*f);
  }
}

// ---------------------------------------------------------------------------
// P4: z[b,i,d] = attn[b,i,:] @ v[b,:,d] + z_a[i,b,d].
__global__ __launch_bounds__(256) void k_zv(
    const float* __restrict__ attn, const float* __restrict__ vf,
    const float* __restrict__ za, float* __restrict__ zout)
{
  __shared__ __align__(16) u16 vt[64 * 40];
  const int t = threadIdx.x, l = t & 63, w = t >> 6;
  const int b = blockIdx.x & 15, it = blockIdx.x >> 4;
  const int lr = l & 15, lg = l >> 4;
  const int iw = it * 64 + w * 16;
  fx4 acc[4];
#pragma unroll
  for (int n = 0; n < 4; ++n) acc[n] = (fx4){0.f, 0.f, 0.f, 0.f};
  const int jl = t >> 3;
  const int c0 = (t & 7) * 8;
  for (int ks = 0; ks < 32; ++ks) {
    const int j0 = ks * 32;
    const float* vp = vf + (size_t)(b * 1024 + j0 + jl) * 64 + c0;
    float4 v0 = *(const float4*)(vp);
    float4 v1 = *(const float4*)(vp + 4);
    __syncthreads();
    vt[(c0 + 0) * 40 + jl] = (u16)b16(v0.x);
    vt[(c0 + 1) * 40 + jl] = (u16)b16(v0.y);
    vt[(c0 + 2) * 40 + jl] = (u16)b16(v0.z);
    vt[(c0 + 3) * 40 + jl] = (u16)b16(v0.w);
    vt[(c0 + 4) * 40 + jl] = (u16)b16(v1.x);
    vt[(c0 + 5) * 40 + jl] = (u16)b16(v1.y);
    vt[(c0 + 6) * 40 + jl] = (u16)b16(v1.z);
    vt[(c0 + 7) * 40 + jl] = (u16)b16(v1.w);
    __syncthreads();
    const float* apr = attn + (size_t)(b * 1024 + iw + lr) * 1024 + j0 + lg * 8;
    float4 t0 = *(const float4*)(apr);
    float4 t1 = *(const float4*)(apr + 4);
    bhalf8 af = pack8(t0, t1);
#pragma unroll
    for (int n = 0; n < 4; ++n) {
      bhalf8 bf = *(const bhalf8*)(vt + (n * 16 + lr) * 40 + lg * 8);
      acc[n] = __builtin_amdgcn_mfma_f32_16x16x32_bf16(af, bf, acc[n], 0, 0, 0);
    }
  }
#pragma unroll
  for (int n = 0; n < 4; ++n) {
#pragma unroll
    for (int r = 0; r < 4; ++r) {
      const int i = iw + lg * 4 + r;
      const int dd = n * 16 + lr;
      zout[((size_t)b * 1024 + i) * 64 + dd] = acc[n][r] + za[((size_t)i * 16 + b) * 64 + dd];
    }
  }
}

// ---------------------------------------------------------------------------
extern "C" void kernel_launch(void* const* d_in, const int* in_sizes, int n_in,
                              void* d_out, int out_size, void* d_ws, size_t ws_size,
                              hipStream_t stream)
{
  const float* x  = (const float*)d_in[0];
  const float* Wq = (const float*)d_in[1];
  const float* Wk = (const float*)d_in[2];
  const float* Wv = (const float*)d_in[3];
  const float* aK = (const float*)d_in[4];
  const float* aV = (const float*)d_in[5];
  float* zout = (float*)d_out;
  float* attn_out = zout + (size_t)16 * 1024 * 64;   // attn after z

  char* ws = (char*)d_ws;                 // layout (44 MB total):
  u16*    qbf = (u16*)(ws);                               //  0.. 2 MB q bf16
  u16*    kbf = (u16*)(ws + (size_t)2  * 1024 * 1024);    //  2.. 4 MB k bf16
  float*  vf  = (float*)(ws + (size_t)4  * 1024 * 1024);  //  4.. 8 MB v fp32
  float*  za  = (float*)(ws + (size_t)8  * 1024 * 1024);  //  8..12 MB z_a [i][b][d]
  __half* qkw = (__half*)(ws + (size_t)12 * 1024 * 1024); // 12..44 MB QK fp16 [i][b][j]

  hipLaunchKernelGGL(k_proj, dim3(256),  dim3(256), 0, stream, x, Wq, Wk, Wv, qbf, kbf, vf);
  hipLaunchKernelGGL(k_qk,   dim3(256),  dim3(256), 0, stream, qbf, kbf, qkw);
  hipLaunchKernelGGL(k_core, dim3(1024), dim3(256), 0, stream, aK, aV, qbf, qkw, attn_out, za);
  hipLaunchKernelGGL(k_zv,   dim3(256),  dim3(256), 0, stream, attn_out, vf, za, zout);
}